// Round 9
// baseline (205.355 us; speedup 1.0000x reference)
//
#include <hip/hip_runtime.h>
#include <hip/hip_bf16.h>

// ---------------------------------------------------------------------------
// IrrepsLinear via bf16 hi/lo-split MFMA (gfx950), round 9.
//   out0 = (x0 @ W0 + modal @ W0m) / sqrt(130)      x0: [N,128], W0: 128x128
//   out1 = einsum('nim,io', x1, W1) / 8             x1: [N,64,3], W1: 64x64
//   out2 = einsum('nim,io', x2, W2) / sqrt(32)      x2: [N,32,5], W2: 32x32
// v = hi + lo (bf16 RNE); v*w ~ vh*wh + vh*wl + vl*wh (3 MFMAs).
// Round-9 deltas vs round 8 (159.5us):
//   - OPERAND-SWAPPED MFMA: acc = mfma(W_frag, x_frag) -> D[o][n] with
//     n=lane&15 (one output row per lane), o=(lane>>4)*4+reg (4 consecutive
//     cols). Per-lane outputs are contiguous floats (A:4, B:12, C:20) ->
//     DIRECT float4 global stores, all complete 64B sectors.
//   - fp32 OUT LDS tile deleted: LDS 49664 -> 24576 B, 6 -> 5 barriers,
//     4 blocks/CU at __launch_bounds__(256,4) (16 waves vs 12).
//   - ws layout and x-tile staging/frag reads unchanged (A/B frag lane
//     layouts are symmetric, so the same register contents serve both roles).
// ---------------------------------------------------------------------------

typedef __attribute__((ext_vector_type(8))) short  short8;   // bf16x8 frag
typedef __attribute__((ext_vector_type(4))) float  f32x4;    // acc frag

#define NTH 256
#define BR  32

// ws layout in ushort units
#define W0H 0
#define W0L 16384
#define W1H 32768
#define W1L 36864
#define W2H 40960
#define W2L 41984
// total 43008 ushorts = 86016 bytes of d_ws

// --------------------------- split helpers ---------------------------------
__device__ __forceinline__ unsigned bc2(__hip_bfloat162 h) {
    unsigned u; __builtin_memcpy(&u, &h, 4); return u;
}

struct HL4 { uint2 h, l; };

__device__ __forceinline__ HL4 split4(float a, float b, float c, float d) {
    __hip_bfloat162 h01 = __float22bfloat162_rn({a, b});
    __hip_bfloat162 h23 = __float22bfloat162_rn({c, d});
    float ra = a - __low2float(h01),  rb = b - __high2float(h01);
    float rc = c - __low2float(h23),  rd = d - __high2float(h23);
    __hip_bfloat162 l01 = __float22bfloat162_rn({ra, rb});
    __hip_bfloat162 l23 = __float22bfloat162_rn({rc, rd});
    HL4 r;
    r.h = make_uint2(bc2(h01), bc2(h23));
    r.l = make_uint2(bc2(l01), bc2(l23));
    return r;
}

__device__ __forceinline__ void split_w(float v, unsigned short& h, unsigned short& l) {
    __hip_bfloat16 hb = __float2bfloat16(v);
    float r = v - __bfloat162float(hb);
    __hip_bfloat16 lb = __float2bfloat16(r);
    __builtin_memcpy(&h, &hb, 2);
    __builtin_memcpy(&l, &lb, 2);
}

// --------------------------- weight prep kernel ----------------------------
// Frag order: slot s = ((ct*NKT + kt)*64 + lane)*8 + j holds W[k][col],
//   col = ct*16 + (lane&15), k = kt*32 + (lane>>4)*8 + j.
// (Same per-lane contents serve as the MFMA *A* operand after the swap.)
__global__ void prep_weights(const float* __restrict__ W0,
                             const float* __restrict__ W1,
                             const float* __restrict__ W2,
                             unsigned short* __restrict__ ws) {
    const int s0     = blockIdx.x * blockDim.x + threadIdx.x;
    const int STRIDE = gridDim.x * blockDim.x;
    for (int s = s0; s < 16384; s += STRIDE) {     // W0: ct 0..7, kt 0..3
        int j = s & 7, l = (s >> 3) & 63, kt = (s >> 9) & 3, ct = s >> 11;
        int col = ct * 16 + (l & 15);
        int k   = kt * 32 + (l >> 4) * 8 + j;
        unsigned short h, lo;
        split_w(W0[k * 128 + col], h, lo);
        ws[W0H + s] = h; ws[W0L + s] = lo;
    }
    for (int s = s0; s < 4096; s += STRIDE) {      // W1: ct 0..3, kt 0..1
        int j = s & 7, l = (s >> 3) & 63, kt = (s >> 9) & 1, ct = s >> 10;
        int col = ct * 16 + (l & 15);
        int k   = kt * 32 + (l >> 4) * 8 + j;
        unsigned short h, lo;
        split_w(W1[k * 64 + col], h, lo);
        ws[W1H + s] = h; ws[W1L + s] = lo;
    }
    for (int s = s0; s < 1024; s += STRIDE) {      // W2: ct 0..1, kt = 0
        int j = s & 7, l = (s >> 3) & 63, ct = s >> 9;
        int col = ct * 16 + (l & 15);
        int k   = (l >> 4) * 8 + j;
        unsigned short h, lo;
        split_w(W2[k * 32 + col], h, lo);
        ws[W2H + s] = h; ws[W2L + s] = lo;
    }
}

#define MFMA(a, b, c) __builtin_amdgcn_mfma_f32_16x16x32_bf16((a), (b), (c), 0, 0, 0)

// ------------------------------ main kernel --------------------------------
// 4 waves/block; wave w: rows rb0=(w>>1)*16, col-half ch=w&1.
// Single IN LDS region (24576 B), reused per phase:
//   A hi@0/lo@8192 ([32][128]bf16, swz (row&7)<<4)
//   B hi m*4096@0 / lo @12288 ([m][32][64], swz (row&7)<<4)
//   C hi m*2048@0 / lo @10240 ([m][32][32], swz (row&3)<<4)
// Lane (r,kg) owns output row n = row0+rb0+r; cols o = ct*16+kg*4+reg.
__global__ __launch_bounds__(NTH, 4) void irreps_mfma_kernel(
    const float* __restrict__ x,
    const float* __restrict__ modal_attr,
    const float* __restrict__ W0m,
    const unsigned short* __restrict__ wsf,
    const int*   __restrict__ batch,
    float*       __restrict__ out,
    int N)
{
    __shared__ __align__(16) char inb[24576];

    const int tid  = threadIdx.x;
    const int w    = tid >> 6;
    const int l    = tid & 63;
    const int r    = l & 15;
    const int kg   = l >> 4;
    const int rb0  = (w >> 1) * 16;
    const int ch   = w & 1;
    const int row0 = blockIdx.x * BR;
    const int arow = rb0 + r;            // x-frag row within tile = my out row

    const int  n_mine = row0 + arow;
    const bool ok     = n_mine < N;
    const int  nc     = ok ? n_mine : N - 1;
    const int  g      = batch[nc];
    const float m0 = modal_attr[2 * g];
    const float m1 = modal_attr[2 * g + 1];
    float* __restrict__ orow = out + (size_t)n_mine * 480;

    const float4* __restrict__ x4 = reinterpret_cast<const float4*>(x);

    // ---- stage+split phase-A input: x[:,0:128) ----
    {
        const int seg = tid & 15;
        const int rr0 = tid >> 4;
        #pragma unroll
        for (int t2 = 0; t2 < 2; ++t2) {
            int rr = rr0 + 16 * t2;
            int n  = row0 + rr; n = n < N ? n : N - 1;
            const float4* src = &x4[(size_t)n * 120 + seg * 2];
            float4 a = src[0], b = src[1];
            HL4 p = split4(a.x, a.y, a.z, a.w);
            HL4 q = split4(b.x, b.y, b.z, b.w);
            int byte = (rr * 256 + seg * 16) ^ ((rr & 7) << 4);
            *reinterpret_cast<uint4*>(inb + byte)        = make_uint4(p.h.x, p.h.y, q.h.x, q.h.y);
            *reinterpret_cast<uint4*>(inb + 8192 + byte) = make_uint4(p.l.x, p.l.y, q.l.x, q.l.y);
        }
    }

    // ---- T14: issue phase-B global loads (fly under compute A) ----
    float4 bld[2][3];
    {
        const int ig  = tid & 15;
        const int rr0 = tid >> 4;
        #pragma unroll
        for (int t2 = 0; t2 < 2; ++t2) {
            int rr = rr0 + 16 * t2;
            int n  = row0 + rr; n = n < N ? n : N - 1;
            const float4* src = &x4[(size_t)n * 120 + 32 + ig * 3];
            bld[t2][0] = src[0]; bld[t2][1] = src[1]; bld[t2][2] = src[2];
        }
    }
    __syncthreads();                                            // bar 1

    // ---- x-frags A (B-operand after swap) ----
    short8 xh[4], xl[4];
    {
        const int sw = (arow & 7) << 4;
        #pragma unroll
        for (int kt = 0; kt < 4; ++kt) {
            int byte = (arow * 256 + kt * 64 + kg * 16) ^ sw;
            xh[kt] = *reinterpret_cast<const short8*>(inb + byte);
            xl[kt] = *reinterpret_cast<const short8*>(inb + 8192 + byte);
        }
    }
    __syncthreads();                                            // bar 2

    // ---- slot: stage B into IN || issue C loads || compute A + store ----
    {
        const int ig  = tid & 15;
        const int rr0 = tid >> 4;
        #pragma unroll
        for (int t2 = 0; t2 < 2; ++t2) {
            int rr = rr0 + 16 * t2;
            float4 f0 = bld[t2][0], f1 = bld[t2][1], f2 = bld[t2][2];
            HL4 s0 = split4(f0.x, f0.w, f1.z, f2.y);   // m=0
            HL4 s1 = split4(f0.y, f1.x, f1.w, f2.z);   // m=1
            HL4 s2 = split4(f0.z, f1.y, f2.x, f2.w);   // m=2
            int rbyte = (rr * 128 + ig * 8) ^ ((rr & 7) << 4);
            *reinterpret_cast<uint2*>(inb + 0 * 4096 + rbyte)         = s0.h;
            *reinterpret_cast<uint2*>(inb + 1 * 4096 + rbyte)         = s1.h;
            *reinterpret_cast<uint2*>(inb + 2 * 4096 + rbyte)         = s2.h;
            *reinterpret_cast<uint2*>(inb + 12288 + 0 * 4096 + rbyte) = s0.l;
            *reinterpret_cast<uint2*>(inb + 12288 + 1 * 4096 + rbyte) = s1.l;
            *reinterpret_cast<uint2*>(inb + 12288 + 2 * 4096 + rbyte) = s2.l;
        }
    }
    float4 cld[5];
    {   // T14: issue phase-C loads (fly under compute A + B)
        int rr = tid >> 3, ig = tid & 7;
        int n  = row0 + rr; n = n < N ? n : N - 1;
        const float4* src = &x4[(size_t)n * 120 + 80 + ig * 5];
        #pragma unroll
        for (int q = 0; q < 5; ++q) cld[q] = src[q];
    }
    {   // compute A: acc = sum_kt mfma(W_frag, x_frag); direct float4 store
        #pragma unroll
        for (int ci = 0; ci < 4; ++ci) {
            int ct = ch * 4 + ci;
            f32x4 acc = {0.f, 0.f, 0.f, 0.f};
            #pragma unroll
            for (int kt = 0; kt < 4; ++kt) {
                int b = ct * 4 + kt;
                short8 wh = *reinterpret_cast<const short8*>(wsf + W0H + (size_t)(b * 64 + l) * 8);
                short8 wl = *reinterpret_cast<const short8*>(wsf + W0L + (size_t)(b * 64 + l) * 8);
                acc = MFMA(wh, xh[kt], acc);
                acc = MFMA(wh, xl[kt], acc);
                acc = MFMA(wl, xh[kt], acc);
            }
            int col0 = ct * 16 + kg * 4;
            float4 wm0 = *reinterpret_cast<const float4*>(W0m + col0);
            float4 wm1 = *reinterpret_cast<const float4*>(W0m + 128 + col0);
            const float inv0 = 0.08770580193070293f;  // 1/sqrt(130)
            float4 o;
            o.x = (acc[0] + m0 * wm0.x + m1 * wm1.x) * inv0;
            o.y = (acc[1] + m0 * wm0.y + m1 * wm1.y) * inv0;
            o.z = (acc[2] + m0 * wm0.z + m1 * wm1.z) * inv0;
            o.w = (acc[3] + m0 * wm0.w + m1 * wm1.w) * inv0;
            if (ok) *reinterpret_cast<float4*>(orow + col0) = o;
        }
    }
    __syncthreads();                                            // bar 3

    // ---- x-frags B ----
    short8 xh1[3][2], xl1[3][2];
    {
        const int sw = (arow & 7) << 4;
        #pragma unroll
        for (int m = 0; m < 3; ++m) {
            #pragma unroll
            for (int kt = 0; kt < 2; ++kt) {
                int byte = (arow * 128 + kt * 64 + kg * 16) ^ sw;
                xh1[m][kt] = *reinterpret_cast<const short8*>(inb + m * 4096 + byte);
                xl1[m][kt] = *reinterpret_cast<const short8*>(inb + 12288 + m * 4096 + byte);
            }
        }
    }
    __syncthreads();                                            // bar 4

    // ---- slot: stage C into IN || compute B + store ----
    {
        int rr = tid >> 3, ig = tid & 7;
        float f[20];
        #pragma unroll
        for (int q = 0; q < 5; ++q) {
            float4 v = cld[q];
            f[q * 4 + 0] = v.x; f[q * 4 + 1] = v.y; f[q * 4 + 2] = v.z; f[q * 4 + 3] = v.w;
        }
        int rbyte = (rr * 64 + ig * 8) ^ ((rr & 3) << 4);
        #pragma unroll
        for (int m = 0; m < 5; ++m) {
            HL4 s = split4(f[m], f[5 + m], f[10 + m], f[15 + m]);
            *reinterpret_cast<uint2*>(inb + m * 2048 + rbyte)         = s.h;
            *reinterpret_cast<uint2*>(inb + 10240 + m * 2048 + rbyte) = s.l;
        }
    }
    {   // compute B: per ci, 3 m-accs; lane's 12 output floats are contiguous
        const float inv1 = 0.125f;
        #pragma unroll
        for (int ci = 0; ci < 2; ++ci) {
            int ct = ch * 2 + ci;
            f32x4 am[3];
            #pragma unroll
            for (int m = 0; m < 3; ++m) {
                f32x4 acc = {0.f, 0.f, 0.f, 0.f};
                #pragma unroll
                for (int kt = 0; kt < 2; ++kt) {
                    int b = ct * 2 + kt;
                    short8 wh = *reinterpret_cast<const short8*>(wsf + W1H + (size_t)(b * 64 + l) * 8);
                    short8 wl = *reinterpret_cast<const short8*>(wsf + W1L + (size_t)(b * 64 + l) * 8);
                    acc = MFMA(wh, xh1[m][kt], acc);
                    acc = MFMA(wh, xl1[m][kt], acc);
                    acc = MFMA(wl, xh1[m][kt], acc);
                }
                am[m] = acc;
            }
            int oc0 = ct * 16 + kg * 4;
            float* p = orow + 128 + 3 * oc0;     // 12 contiguous floats, 16B-aligned
            if (ok) {
                *reinterpret_cast<float4*>(p) =
                    make_float4(am[0][0] * inv1, am[1][0] * inv1, am[2][0] * inv1, am[0][1] * inv1);
                *reinterpret_cast<float4*>(p + 4) =
                    make_float4(am[1][1] * inv1, am[2][1] * inv1, am[0][2] * inv1, am[1][2] * inv1);
                *reinterpret_cast<float4*>(p + 8) =
                    make_float4(am[2][2] * inv1, am[0][3] * inv1, am[1][3] * inv1, am[2][3] * inv1);
            }
        }
    }
    __syncthreads();                                            // bar 5

    // ---- x-frags C + compute C + store ----
    {
        const int sw2 = (arow & 3) << 4;
        short8 xh2[5], xl2[5];
        #pragma unroll
        for (int m = 0; m < 5; ++m) {
            int byte = (arow * 64 + kg * 16) ^ sw2;
            xh2[m] = *reinterpret_cast<const short8*>(inb + m * 2048 + byte);
            xl2[m] = *reinterpret_cast<const short8*>(inb + 10240 + m * 2048 + byte);
        }
        int ct = ch;
        short8 wh = *reinterpret_cast<const short8*>(wsf + W2H + (size_t)(ct * 64 + l) * 8);
        short8 wl = *reinterpret_cast<const short8*>(wsf + W2L + (size_t)(ct * 64 + l) * 8);
        f32x4 am[5];
        #pragma unroll
        for (int m = 0; m < 5; ++m) {
            f32x4 acc = {0.f, 0.f, 0.f, 0.f};
            acc = MFMA(wh, xh2[m], acc);
            acc = MFMA(wh, xl2[m], acc);
            acc = MFMA(wl, xh2[m], acc);
            am[m] = acc;
        }
        const float inv2 = 0.17677669529663687f;   // 1/sqrt(32)
        int oc0 = ct * 16 + kg * 4;
        float* p = orow + 320 + 5 * oc0;           // 20 contiguous floats, 16B-aligned
        if (ok) {
            *reinterpret_cast<float4*>(p) =
                make_float4(am[0][0] * inv2, am[1][0] * inv2, am[2][0] * inv2, am[3][0] * inv2);
            *reinterpret_cast<float4*>(p + 4) =
                make_float4(am[4][0] * inv2, am[0][1] * inv2, am[1][1] * inv2, am[2][1] * inv2);
            *reinterpret_cast<float4*>(p + 8) =
                make_float4(am[3][1] * inv2, am[4][1] * inv2, am[0][2] * inv2, am[1][2] * inv2);
            *reinterpret_cast<float4*>(p + 12) =
                make_float4(am[2][2] * inv2, am[3][2] * inv2, am[4][2] * inv2, am[0][3] * inv2);
            *reinterpret_cast<float4*>(p + 16) =
                make_float4(am[1][3] * inv2, am[2][3] * inv2, am[3][3] * inv2, am[4][3] * inv2);
        }
    }
}

extern "C" void kernel_launch(void* const* d_in, const int* in_sizes, int n_in,
                              void* d_out, int out_size, void* d_ws, size_t ws_size,
                              hipStream_t stream) {
    const float* x     = (const float*)d_in[0];
    const float* modal = (const float*)d_in[1];
    const float* W0    = (const float*)d_in[2];
    const float* W0m   = (const float*)d_in[3];
    const float* W1    = (const float*)d_in[4];
    const float* W2    = (const float*)d_in[5];
    const int*   batch = (const int*)d_in[6];
    float* out = (float*)d_out;
    unsigned short* ws = (unsigned short*)d_ws;   // needs 86016 B

    const int N    = in_sizes[6];                 // 200000
    const int grid = (N + BR - 1) / BR;           // 6250 blocks

    prep_weights<<<84, NTH, 0, stream>>>(W0, W1, W2, ws);
    irreps_mfma_kernel<<<grid, NTH, 0, stream>>>(x, modal, W0m, ws, batch, out, N);
}

// Round 10
// 199.843 us; speedup vs baseline: 1.0276x; 1.0276x over previous
//
#include <hip/hip_runtime.h>
#include <hip/hip_bf16.h>

// ---------------------------------------------------------------------------
// IrrepsLinear via bf16 hi/lo-split MFMA (gfx950), round 10.
//   out0 = (x0 @ W0 + modal @ W0m) / sqrt(130)      x0: [N,128], W0: 128x128
//   out1 = einsum('nim,io', x1, W1) / 8             x1: [N,64,3], W1: 64x64
//   out2 = einsum('nim,io', x2, W2) / sqrt(32)      x2: [N,32,5], W2: 32x32
// v = hi + lo (bf16 RNE); v*w ~ vh*wh + vh*wl + vl*wh (3 MFMAs).
// Round-10 deltas:
//   - Keep r9's operand-swapped MFMA (numerics proven: absmax 0.03125,
//     direct contiguous float4 stores, no OUT-LDS tile).
//   - FIX r9's regression: __launch_bounds__(256,3) (r9's (256,4) -> VGPR=64,
//     T14 prefetch regs sunk past barriers -> latency-bound 205us; r8's
//     (256,3) empirically preserved prefetch).
//   - Double-buffered IN LDS: buf0 = A/C tile (20480B), buf1 = B tile
//     (24576B), total 45056B. stage(P+1) writes the other buffer than
//     compute(P) reads -> 3 barriers total (r8 had 6).
// ---------------------------------------------------------------------------

typedef __attribute__((ext_vector_type(8))) short  short8;   // bf16x8 frag
typedef __attribute__((ext_vector_type(4))) float  f32x4;    // acc frag

#define NTH 256
#define BR  32

// ws layout in ushort units
#define W0H 0
#define W0L 16384
#define W1H 32768
#define W1L 36864
#define W2H 40960
#define W2L 41984
// total 43008 ushorts = 86016 bytes of d_ws

// --------------------------- split helpers ---------------------------------
__device__ __forceinline__ unsigned bc2(__hip_bfloat162 h) {
    unsigned u; __builtin_memcpy(&u, &h, 4); return u;
}

struct HL4 { uint2 h, l; };

__device__ __forceinline__ HL4 split4(float a, float b, float c, float d) {
    __hip_bfloat162 h01 = __float22bfloat162_rn({a, b});
    __hip_bfloat162 h23 = __float22bfloat162_rn({c, d});
    float ra = a - __low2float(h01),  rb = b - __high2float(h01);
    float rc = c - __low2float(h23),  rd = d - __high2float(h23);
    __hip_bfloat162 l01 = __float22bfloat162_rn({ra, rb});
    __hip_bfloat162 l23 = __float22bfloat162_rn({rc, rd});
    HL4 r;
    r.h = make_uint2(bc2(h01), bc2(h23));
    r.l = make_uint2(bc2(l01), bc2(l23));
    return r;
}

__device__ __forceinline__ void split_w(float v, unsigned short& h, unsigned short& l) {
    __hip_bfloat16 hb = __float2bfloat16(v);
    float r = v - __bfloat162float(hb);
    __hip_bfloat16 lb = __float2bfloat16(r);
    __builtin_memcpy(&h, &hb, 2);
    __builtin_memcpy(&l, &lb, 2);
}

// --------------------------- weight prep kernel ----------------------------
// Frag order: slot s = ((ct*NKT + kt)*64 + lane)*8 + j holds W[k][col],
//   col = ct*16 + (lane&15), k = kt*32 + (lane>>4)*8 + j.
// (Per-lane contents serve as the MFMA *A* operand in the swapped scheme.)
__global__ void prep_weights(const float* __restrict__ W0,
                             const float* __restrict__ W1,
                             const float* __restrict__ W2,
                             unsigned short* __restrict__ ws) {
    const int s0     = blockIdx.x * blockDim.x + threadIdx.x;
    const int STRIDE = gridDim.x * blockDim.x;
    for (int s = s0; s < 16384; s += STRIDE) {     // W0: ct 0..7, kt 0..3
        int j = s & 7, l = (s >> 3) & 63, kt = (s >> 9) & 3, ct = s >> 11;
        int col = ct * 16 + (l & 15);
        int k   = kt * 32 + (l >> 4) * 8 + j;
        unsigned short h, lo;
        split_w(W0[k * 128 + col], h, lo);
        ws[W0H + s] = h; ws[W0L + s] = lo;
    }
    for (int s = s0; s < 4096; s += STRIDE) {      // W1: ct 0..3, kt 0..1
        int j = s & 7, l = (s >> 3) & 63, kt = (s >> 9) & 1, ct = s >> 10;
        int col = ct * 16 + (l & 15);
        int k   = kt * 32 + (l >> 4) * 8 + j;
        unsigned short h, lo;
        split_w(W1[k * 64 + col], h, lo);
        ws[W1H + s] = h; ws[W1L + s] = lo;
    }
    for (int s = s0; s < 1024; s += STRIDE) {      // W2: ct 0..1, kt = 0
        int j = s & 7, l = (s >> 3) & 63, ct = s >> 9;
        int col = ct * 16 + (l & 15);
        int k   = (l >> 4) * 8 + j;
        unsigned short h, lo;
        split_w(W2[k * 32 + col], h, lo);
        ws[W2H + s] = h; ws[W2L + s] = lo;
    }
}

#define MFMA(a, b, c) __builtin_amdgcn_mfma_f32_16x16x32_bf16((a), (b), (c), 0, 0, 0)

// ------------------------------ main kernel --------------------------------
// 4 waves/block; wave w: col-half ch=w&1, row-group rb0=(w>>1)*16.
// buf0: A hi@0/lo@8192 ([32][128]bf16, swz (row&7)<<4)
//       C hi m*2048@0 / lo @10240 ([m][32][32], swz (row&3)<<4)
// buf1: B hi m*4096@0 / lo @12288 ([m][32][64], swz (row&7)<<4)
// Lane (r,kg): output row n = row0+rb0+r; cols o = ct*16+kg*4+reg.
__global__ __launch_bounds__(NTH, 3) void irreps_mfma_kernel(
    const float* __restrict__ x,
    const float* __restrict__ modal_attr,
    const float* __restrict__ W0m,
    const unsigned short* __restrict__ wsf,
    const int*   __restrict__ batch,
    float*       __restrict__ out,
    int N)
{
    __shared__ __align__(16) char ldsb[45056];
    char* buf0 = ldsb;            // A tile (16384 B) then C tile (20480 B)
    char* buf1 = ldsb + 20480;    // B tile (24576 B)

    const int tid  = threadIdx.x;
    const int w    = tid >> 6;
    const int l    = tid & 63;
    const int r    = l & 15;
    const int kg   = l >> 4;
    const int rb0  = (w >> 1) * 16;
    const int ch   = w & 1;
    const int row0 = blockIdx.x * BR;
    const int arow = rb0 + r;            // x-frag row within tile = my out row

    const int  n_mine = row0 + arow;
    const bool ok     = n_mine < N;
    const int  nc     = ok ? n_mine : N - 1;
    const int  g      = batch[nc];
    const float m0 = modal_attr[2 * g];
    const float m1 = modal_attr[2 * g + 1];
    float* __restrict__ orow = out + (size_t)n_mine * 480;

    const float4* __restrict__ x4 = reinterpret_cast<const float4*>(x);

    // ---- stage+split phase-A input: x[:,0:128) -> buf0 ----
    {
        const int seg = tid & 15;
        const int rr0 = tid >> 4;
        #pragma unroll
        for (int t2 = 0; t2 < 2; ++t2) {
            int rr = rr0 + 16 * t2;
            int n  = row0 + rr; n = n < N ? n : N - 1;
            const float4* src = &x4[(size_t)n * 120 + seg * 2];
            float4 a = src[0], b = src[1];
            HL4 p = split4(a.x, a.y, a.z, a.w);
            HL4 q = split4(b.x, b.y, b.z, b.w);
            int byte = (rr * 256 + seg * 16) ^ ((rr & 7) << 4);
            *reinterpret_cast<uint4*>(buf0 + byte)        = make_uint4(p.h.x, p.h.y, q.h.x, q.h.y);
            *reinterpret_cast<uint4*>(buf0 + 8192 + byte) = make_uint4(p.l.x, p.l.y, q.l.x, q.l.y);
        }
    }

    // ---- T14: issue phase-B global loads (fly under compute A) ----
    float4 bld[2][3];
    {
        const int ig  = tid & 15;
        const int rr0 = tid >> 4;
        #pragma unroll
        for (int t2 = 0; t2 < 2; ++t2) {
            int rr = rr0 + 16 * t2;
            int n  = row0 + rr; n = n < N ? n : N - 1;
            const float4* src = &x4[(size_t)n * 120 + 32 + ig * 3];
            bld[t2][0] = src[0]; bld[t2][1] = src[1]; bld[t2][2] = src[2];
        }
    }
    __syncthreads();                                            // bar 1

    // ======== slot 1: fragsA + computeA/store || issue C || splitB->buf1 ====
    {
        const int sw = (arow & 7) << 4;
        short8 xh[4], xl[4];
        #pragma unroll
        for (int kt = 0; kt < 4; ++kt) {
            int byte = (arow * 256 + kt * 64 + kg * 16) ^ sw;
            xh[kt] = *reinterpret_cast<const short8*>(buf0 + byte);
            xl[kt] = *reinterpret_cast<const short8*>(buf0 + 8192 + byte);
        }
        #pragma unroll
        for (int ci = 0; ci < 4; ++ci) {
            int ct = ch * 4 + ci;
            f32x4 acc = {0.f, 0.f, 0.f, 0.f};
            #pragma unroll
            for (int kt = 0; kt < 4; ++kt) {
                int b = ct * 4 + kt;
                short8 wh = *reinterpret_cast<const short8*>(wsf + W0H + (size_t)(b * 64 + l) * 8);
                short8 wl = *reinterpret_cast<const short8*>(wsf + W0L + (size_t)(b * 64 + l) * 8);
                acc = MFMA(wh, xh[kt], acc);
                acc = MFMA(wh, xl[kt], acc);
                acc = MFMA(wl, xh[kt], acc);
            }
            int col0 = ct * 16 + kg * 4;
            float4 wm0 = *reinterpret_cast<const float4*>(W0m + col0);
            float4 wm1 = *reinterpret_cast<const float4*>(W0m + 128 + col0);
            const float inv0 = 0.08770580193070293f;  // 1/sqrt(130)
            float4 o;
            o.x = (acc[0] + m0 * wm0.x + m1 * wm1.x) * inv0;
            o.y = (acc[1] + m0 * wm0.y + m1 * wm1.y) * inv0;
            o.z = (acc[2] + m0 * wm0.z + m1 * wm1.z) * inv0;
            o.w = (acc[3] + m0 * wm0.w + m1 * wm1.w) * inv0;
            if (ok) *reinterpret_cast<float4*>(orow + col0) = o;
        }
    }
    float4 cld[5];
    {   // T14: issue phase-C loads (fly under splitB + computeB)
        int rr = tid >> 3, ig = tid & 7;
        int n  = row0 + rr; n = n < N ? n : N - 1;
        const float4* src = &x4[(size_t)n * 120 + 80 + ig * 5];
        #pragma unroll
        for (int q = 0; q < 5; ++q) cld[q] = src[q];
    }
    {   // split+write B tile -> buf1 (bld consumed: vmcnt leaves cld in flight)
        const int ig  = tid & 15;
        const int rr0 = tid >> 4;
        #pragma unroll
        for (int t2 = 0; t2 < 2; ++t2) {
            int rr = rr0 + 16 * t2;
            float4 f0 = bld[t2][0], f1 = bld[t2][1], f2 = bld[t2][2];
            HL4 s0 = split4(f0.x, f0.w, f1.z, f2.y);   // m=0
            HL4 s1 = split4(f0.y, f1.x, f1.w, f2.z);   // m=1
            HL4 s2 = split4(f0.z, f1.y, f2.x, f2.w);   // m=2
            int rbyte = (rr * 128 + ig * 8) ^ ((rr & 7) << 4);
            *reinterpret_cast<uint2*>(buf1 + 0 * 4096 + rbyte)         = s0.h;
            *reinterpret_cast<uint2*>(buf1 + 1 * 4096 + rbyte)         = s1.h;
            *reinterpret_cast<uint2*>(buf1 + 2 * 4096 + rbyte)         = s2.h;
            *reinterpret_cast<uint2*>(buf1 + 12288 + 0 * 4096 + rbyte) = s0.l;
            *reinterpret_cast<uint2*>(buf1 + 12288 + 1 * 4096 + rbyte) = s1.l;
            *reinterpret_cast<uint2*>(buf1 + 12288 + 2 * 4096 + rbyte) = s2.l;
        }
    }
    __syncthreads();                                            // bar 2

    // ======== slot 2: fragsB + computeB/store || splitC->buf0 ==============
    {
        const int sw = (arow & 7) << 4;
        short8 xh1[3][2], xl1[3][2];
        #pragma unroll
        for (int m = 0; m < 3; ++m) {
            #pragma unroll
            for (int kt = 0; kt < 2; ++kt) {
                int byte = (arow * 128 + kt * 64 + kg * 16) ^ sw;
                xh1[m][kt] = *reinterpret_cast<const short8*>(buf1 + m * 4096 + byte);
                xl1[m][kt] = *reinterpret_cast<const short8*>(buf1 + 12288 + m * 4096 + byte);
            }
        }
        const float inv1 = 0.125f;
        #pragma unroll
        for (int ci = 0; ci < 2; ++ci) {
            int ct = ch * 2 + ci;
            short8 bh[2], bl[2];
            #pragma unroll
            for (int kt = 0; kt < 2; ++kt) {
                int b = ct * 2 + kt;
                bh[kt] = *reinterpret_cast<const short8*>(wsf + W1H + (size_t)(b * 64 + l) * 8);
                bl[kt] = *reinterpret_cast<const short8*>(wsf + W1L + (size_t)(b * 64 + l) * 8);
            }
            f32x4 am[3];
            #pragma unroll
            for (int m = 0; m < 3; ++m) {
                f32x4 acc = {0.f, 0.f, 0.f, 0.f};
                #pragma unroll
                for (int kt = 0; kt < 2; ++kt) {
                    acc = MFMA(bh[kt], xh1[m][kt], acc);
                    acc = MFMA(bh[kt], xl1[m][kt], acc);
                    acc = MFMA(bl[kt], xh1[m][kt], acc);
                }
                am[m] = acc;
            }
            int oc0 = ct * 16 + kg * 4;
            float* p = orow + 128 + 3 * oc0;     // 12 contiguous floats, 16B-aligned
            if (ok) {
                *reinterpret_cast<float4*>(p) =
                    make_float4(am[0][0] * inv1, am[1][0] * inv1, am[2][0] * inv1, am[0][1] * inv1);
                *reinterpret_cast<float4*>(p + 4) =
                    make_float4(am[1][1] * inv1, am[2][1] * inv1, am[0][2] * inv1, am[1][2] * inv1);
                *reinterpret_cast<float4*>(p + 8) =
                    make_float4(am[2][2] * inv1, am[0][3] * inv1, am[1][3] * inv1, am[2][3] * inv1);
            }
        }
    }
    {   // split+write C tile -> buf0 (A-tile reads finished before bar2)
        int rr = tid >> 3, ig = tid & 7;
        float f[20];
        #pragma unroll
        for (int q = 0; q < 5; ++q) {
            float4 v = cld[q];
            f[q * 4 + 0] = v.x; f[q * 4 + 1] = v.y; f[q * 4 + 2] = v.z; f[q * 4 + 3] = v.w;
        }
        int rbyte = (rr * 64 + ig * 8) ^ ((rr & 3) << 4);
        #pragma unroll
        for (int m = 0; m < 5; ++m) {
            HL4 s = split4(f[m], f[5 + m], f[10 + m], f[15 + m]);
            *reinterpret_cast<uint2*>(buf0 + m * 2048 + rbyte)         = s.h;
            *reinterpret_cast<uint2*>(buf0 + 10240 + m * 2048 + rbyte) = s.l;
        }
    }
    __syncthreads();                                            // bar 3

    // ======== slot 3: fragsC + computeC/store ==============================
    {
        const int sw2 = (arow & 3) << 4;
        short8 xh2[5], xl2[5];
        #pragma unroll
        for (int m = 0; m < 5; ++m) {
            int byte = (arow * 64 + kg * 16) ^ sw2;
            xh2[m] = *reinterpret_cast<const short8*>(buf0 + m * 2048 + byte);
            xl2[m] = *reinterpret_cast<const short8*>(buf0 + 10240 + m * 2048 + byte);
        }
        int ct = ch;
        short8 wh = *reinterpret_cast<const short8*>(wsf + W2H + (size_t)(ct * 64 + l) * 8);
        short8 wl = *reinterpret_cast<const short8*>(wsf + W2L + (size_t)(ct * 64 + l) * 8);
        f32x4 am[5];
        #pragma unroll
        for (int m = 0; m < 5; ++m) {
            f32x4 acc = {0.f, 0.f, 0.f, 0.f};
            acc = MFMA(wh, xh2[m], acc);
            acc = MFMA(wh, xl2[m], acc);
            acc = MFMA(wl, xh2[m], acc);
            am[m] = acc;
        }
        const float inv2 = 0.17677669529663687f;   // 1/sqrt(32)
        int oc0 = ct * 16 + kg * 4;
        float* p = orow + 320 + 5 * oc0;           // 20 contiguous floats, 16B-aligned
        if (ok) {
            *reinterpret_cast<float4*>(p) =
                make_float4(am[0][0] * inv2, am[1][0] * inv2, am[2][0] * inv2, am[3][0] * inv2);
            *reinterpret_cast<float4*>(p + 4) =
                make_float4(am[4][0] * inv2, am[0][1] * inv2, am[1][1] * inv2, am[2][1] * inv2);
            *reinterpret_cast<float4*>(p + 8) =
                make_float4(am[3][1] * inv2, am[4][1] * inv2, am[0][2] * inv2, am[1][2] * inv2);
            *reinterpret_cast<float4*>(p + 12) =
                make_float4(am[2][2] * inv2, am[3][2] * inv2, am[4][2] * inv2, am[0][3] * inv2);
            *reinterpret_cast<float4*>(p + 16) =
                make_float4(am[1][3] * inv2, am[2][3] * inv2, am[3][3] * inv2, am[4][3] * inv2);
        }
    }
}

extern "C" void kernel_launch(void* const* d_in, const int* in_sizes, int n_in,
                              void* d_out, int out_size, void* d_ws, size_t ws_size,
                              hipStream_t stream) {
    const float* x     = (const float*)d_in[0];
    const float* modal = (const float*)d_in[1];
    const float* W0    = (const float*)d_in[2];
    const float* W0m   = (const float*)d_in[3];
    const float* W1    = (const float*)d_in[4];
    const float* W2    = (const float*)d_in[5];
    const int*   batch = (const int*)d_in[6];
    float* out = (float*)d_out;
    unsigned short* ws = (unsigned short*)d_ws;   // needs 86016 B

    const int N    = in_sizes[6];                 // 200000
    const int grid = (N + BR - 1) / BR;           // 6250 blocks

    prep_weights<<<84, NTH, 0, stream>>>(W0, W1, W2, ws);
    irreps_mfma_kernel<<<grid, NTH, 0, stream>>>(x, modal, W0m, ws, batch, out, N);
}